// Round 1
// baseline (222.713 us; speedup 1.0000x reference)
//
#include <hip/hip_runtime.h>
#include <math.h>

#define SQ    1024
#define INF   128
#define OUTF  64
#define OHH   256
#define LOG2E 1.44269504088896f

using bf16x8 = __attribute__((ext_vector_type(8))) __bf16;
using bf16x4 = __attribute__((ext_vector_type(4))) __bf16;
using f32x4  = __attribute__((ext_vector_type(4))) float;
using u16x8  = __attribute__((ext_vector_type(8))) unsigned short;

#if __has_builtin(__builtin_amdgcn_exp2f)
#define EXP2F(x) __builtin_amdgcn_exp2f(x)
#else
#define EXP2F(x) __expf((x) * 0.6931471805599453f)
#endif

// ---------------------------------------------------------------------------
// Kernel A (unchanged math): per 64-row tile of flattened (N*S, INF) h:
//   WhM = h @ mean-over-heads(W) via 3-term split bf16 MFMA, stored to global
//   in B-frag order; f' and g' (pre-scaled by log2e) via fp32 dots.
// Block remap: batch (bx&31) -> XCD bx%8, matching kC's pinning so WhM is
// produced and consumed on the same XCD's L2 where possible.
// ---------------------------------------------------------------------------
__global__ __launch_bounds__(256) void kA(
    const float* __restrict__ h, const float* __restrict__ W,
    const float* __restrict__ a, __bf16* __restrict__ whmH,
    __bf16* __restrict__ whmL, float* __restrict__ fo, float* __restrict__ go)
{
    __shared__ __bf16 wmfH[8192];       // [c][T][lane*8+idx] B-frag hi (16 KB)
    __shared__ __bf16 wmfL[8192];       // lo residual (16 KB)
    __shared__ float  wfl[INF], wgl[INF]; // prescaled by LOG2E
    __shared__ float  al[2 * OHH];

    const int t    = threadIdx.x;
    const int lane = t & 63;
    const int w    = t >> 6;
    const int bx   = blockIdx.x;
    // batch = bx&31 (XCD = bx%8), tile-in-batch = bx>>5; never straddles batch
    const int R0   = ((bx & 31) << 10) + ((bx >> 5) << 6);

    // stage a
    al[t]       = a[t];
    al[t + 256] = a[t + 256];

    // WM in B-frag layout, hi/lo split (RNE): 2048 float4-groups
    for (int g = t; g < 2048; g += 256) {
        const int k  = g >> 4;
        const int n0 = (g & 15) << 2;
        const float* Wp = W + k * OHH + n0;
        float4 w0 = *(const float4*)Wp;
        float4 w1 = *(const float4*)(Wp + 64);
        float4 w2 = *(const float4*)(Wp + 128);
        float4 w3 = *(const float4*)(Wp + 192);
        float wm4[4] = {0.25f * (w0.x + w1.x + w2.x + w3.x),
                        0.25f * (w0.y + w1.y + w2.y + w3.y),
                        0.25f * (w0.z + w1.z + w2.z + w3.z),
                        0.25f * (w0.w + w1.w + w2.w + w3.w)};
        const int c = k >> 5, kq = (k >> 3) & 3, id8 = k & 7, T = n0 >> 4;
        const int lbase = kq * 16 + (n0 & 15);
        #pragma unroll
        for (int j = 0; j < 4; ++j) {
            float  v  = wm4[j];
            __bf16 hb = (__bf16)v;                 // RNE hi
            const int o = ((c * 4 + T) * 64 + lbase + j) * 8 + id8;
            wmfH[o] = hb;
            wmfL[o] = (__bf16)(v - (float)hb);     // residual
        }
    }
    __syncthreads();   // al + wmf ready

    // w_f (t<128) / w_g (t>=128): one 256-dot each; W rows L1/L2-hot
    {
        const int row = t & 127;
        const float4* Wr = (const float4*)(W + row * OHH);
        const float4* av = (const float4*)(t < 128 ? al : al + OHH);
        float s = 0.f;
        for (int q = 0; q < OHH / 4; ++q) {
            float4 wv = Wr[q], x = av[q];
            s += wv.x * x.x + wv.y * x.y + wv.z * x.z + wv.w * x.w;
        }
        if (t < 128) wfl[row] = s * LOG2E;
        else         wgl[row] = s * LOG2E;
    }
    __syncthreads();   // wfl/wgl ready

    // main: A-frag rows direct from global, 3-term split MFMA
    const int m  = lane & 15;
    const int kq = lane >> 4;
    const float* hrow = h + (size_t)(R0 + w * 16 + m) * INF + kq * 8;

    f32x4 acc[4] = {};
    float sf = 0.f, sg = 0.f;

    #pragma unroll
    for (int c = 0; c < 4; ++c) {
        float4 v0 = *(const float4*)(hrow + c * 32);
        float4 v1 = *(const float4*)(hrow + c * 32 + 4);
        float hv[8] = {v0.x, v0.y, v0.z, v0.w, v1.x, v1.y, v1.z, v1.w};

        float4 wf0 = *(const float4*)(wfl + c * 32 + kq * 8);
        float4 wf1 = *(const float4*)(wfl + c * 32 + kq * 8 + 4);
        float4 wg0 = *(const float4*)(wgl + c * 32 + kq * 8);
        float4 wg1 = *(const float4*)(wgl + c * 32 + kq * 8 + 4);
        float wfv[8] = {wf0.x, wf0.y, wf0.z, wf0.w, wf1.x, wf1.y, wf1.z, wf1.w};
        float wgv[8] = {wg0.x, wg0.y, wg0.z, wg0.w, wg1.x, wg1.y, wg1.z, wg1.w};

        u16x8  ahu;
        bf16x8 alo;
        #pragma unroll
        for (int i = 0; i < 8; ++i) {
            float v = hv[i];
            sf = fmaf(v, wfv[i], sf);
            sg = fmaf(v, wgv[i], sg);
            unsigned u = __float_as_uint(v);
            ahu[i] = (unsigned short)(u >> 16);                      // trunc hi
            alo[i] = (__bf16)(v - __uint_as_float(u & 0xFFFF0000u)); // exact resid
        }
        bf16x8 ah = __builtin_bit_cast(bf16x8, ahu);

        #pragma unroll
        for (int T = 0; T < 4; ++T) {
            bf16x8 bh = *(const bf16x8*)&wmfH[((c * 4 + T) * 64 + lane) * 8];
            bf16x8 bl = *(const bf16x8*)&wmfL[((c * 4 + T) * 64 + lane) * 8];
            acc[T] = __builtin_amdgcn_mfma_f32_16x16x32_bf16(ah,  bh, acc[T], 0, 0, 0);
            acc[T] = __builtin_amdgcn_mfma_f32_16x16x32_bf16(alo, bh, acc[T], 0, 0, 0);
            acc[T] = __builtin_amdgcn_mfma_f32_16x16x32_bf16(ah,  bl, acc[T], 0, 0, 0);
        }
    }

    // f,g: sum the 4 k-strips (lanes m, m+16, m+32, m+48)
    sf += __shfl_xor(sf, 16, 64); sf += __shfl_xor(sf, 32, 64);
    sg += __shfl_xor(sg, 16, 64); sg += __shfl_xor(sg, 32, 64);
    if (lane < 16) {
        fo[R0 + w * 16 + m] = sf;
        go[R0 + w * 16 + m] = sg;
    }

    // epilogue: C/D (row = kq*4+r, col = m) -> B-frag flat store, hi/lo split
    {
        const int n     = R0 >> 10;
        const int Jb    = ((R0 & 1023) >> 5) + (w >> 1);
        const int jj3   = 2 * (w & 1) + (kq >> 1);  // (j&31)>>3, r-invariant
        const int laneS = jj3 * 16 + m;
        const int idx0  = (kq & 1) * 4;             // idx' = 4*(kq&1)+r
        #pragma unroll
        for (int T = 0; T < 4; ++T) {
            const size_t base =
                (((size_t)(n * 32 + Jb) * 4 + T) * 64 + laneS) * 8 + idx0;
            bf16x4 hv, lv;
            #pragma unroll
            for (int r = 0; r < 4; ++r) {
                float  v  = acc[T][r];
                __bf16 hb = (__bf16)v;               // RNE hi
                hv[r] = hb;
                lv[r] = (__bf16)(v - (float)hb);     // exact residual
            }
            *(bf16x4*)(whmH + base) = hv;
            *(bf16x4*)(whmL + base) = lv;
        }
    }
}

// ---------------------------------------------------------------------------
// Kernel C, barrier-free rewrite:
//   out = softmax_j(lrelu(f_i+g_j)) @ WhM
// Old structure: LDS ring + one __syncthreads per J (32 barriers, each
// draining vmcnt(0) across all waves) -> 2-phase lockstep at 2 waves/SIMD.
// New structure:
//   - B-fragments (WhM hi/lo, already stored in B-frag order) loaded DIRECTLY
//     from global into VGPRs (coalesced dwordx4, L2-resident: 1 MB/XCD via
//     the n = bx&31 XCD pinning). No LDS staging, no main-loop barriers.
//   - Each wave covers 32 i-rows (2 A-frags) -> each B-frag reused twice,
//     halving L2 B-traffic vs 16-row waves.
//   - The two waves of a row-pair split the J range (split-K); partials are
//     combined once at the end via a 16 KB LDS exchange (1 barrier total).
//   - B loads double-buffered one J ahead so L2 latency hides under P-gen.
// ---------------------------------------------------------------------------
__global__ __launch_bounds__(256, 2) void kC(
    const __bf16* __restrict__ whmH, const __bf16* __restrict__ whmL,
    const float* __restrict__ fi, const float* __restrict__ gi,
    float* __restrict__ out)
{
    __shared__ float gl[SQ];                // g' for this batch (4 KB)
    __shared__ float fl[64];                // f' for this i-tile
    __shared__ f32x4 accX[4][4][64];        // cross-wave partial exchange (16 KB)
    __shared__ float lsW[4][2][16];         // per-wave reduced row-sums

    const int t     = threadIdx.x;
    const int lane  = t & 63;
    const int wid   = t >> 6;
    const int p     = wid >> 1;             // row-pair: rows i0 + p*32 ..
    const int jh    = wid & 1;              // J-half handled by this wave
    const int n     = blockIdx.x & 31;      // batch pinned per XCD (bx%8)
    const int itile = blockIdx.x >> 5;
    const int i0    = itile * 64;

    ((float4*)gl)[t] = ((const float4*)(gi + n * SQ))[t];
    if (t < 64) fl[t] = fi[n * SQ + i0 + t];
    __syncthreads();

    const int m  = lane & 15;
    const int kq = lane >> 4;
    const float myf0 = fl[p * 32 + m];        // A-frag row for rt=0
    const float myf1 = fl[p * 32 + 16 + m];   // A-frag row for rt=1

    // B-frag base: elem ((n*32+J)*4+T)*512 + lane*8  ==  bf16x8 unit
    //              (n*32+J)*256 + T*64 + lane
    const bf16x8* BH = (const bf16x8*)whmH + (size_t)n * 8192 + lane;
    const bf16x8* BL = (const bf16x8*)whmL + (size_t)n * 8192 + lane;

    f32x4 acc[2][4] = {};                   // [rt][T], static-indexed only
    float ls0 = 0.f, ls1 = 0.f;
    const int J0 = jh * 16;

    auto loadB = [&](int J, bf16x8* bh, bf16x8* bl) {
        const bf16x8* ph_ = BH + (size_t)J * 256;
        const bf16x8* pl_ = BL + (size_t)J * 256;
        #pragma unroll
        for (int T = 0; T < 4; ++T) { bh[T] = ph_[T * 64]; bl[T] = pl_[T * 64]; }
    };

    auto compute = [&](int J, const bf16x8* bh, const bf16x8* bl) {
        float4 g0 = *(const float4*)&gl[J * 32 + kq * 8];
        float4 g1 = *(const float4*)&gl[J * 32 + kq * 8 + 4];
        float gs8[8] = {g0.x, g0.y, g0.z, g0.w, g1.x, g1.y, g1.z, g1.w};

        u16x8  phu0, phu1;
        bf16x8 pl0, pl1;
        #pragma unroll
        for (int idx = 0; idx < 8; ++idx) {
            float e0 = myf0 + gs8[idx];
            float r0 = fmaxf(e0, 0.1f * e0);          // lrelu (log2 domain)
            float p0 = EXP2F(r0);
            ls0 += p0;
            unsigned u0 = __float_as_uint(p0);
            phu0[idx] = (unsigned short)(u0 >> 16);   // trunc hi
            pl0[idx]  = (__bf16)(p0 - __uint_as_float(u0 & 0xFFFF0000u));

            float e1 = myf1 + gs8[idx];
            float r1 = fmaxf(e1, 0.1f * e1);
            float p1 = EXP2F(r1);
            ls1 += p1;
            unsigned u1 = __float_as_uint(p1);
            phu1[idx] = (unsigned short)(u1 >> 16);
            pl1[idx]  = (__bf16)(p1 - __uint_as_float(u1 & 0xFFFF0000u));
        }
        bf16x8 ph0 = __builtin_bit_cast(bf16x8, phu0);
        bf16x8 ph1 = __builtin_bit_cast(bf16x8, phu1);

        #pragma unroll
        for (int T = 0; T < 4; ++T) {
            acc[0][T] = __builtin_amdgcn_mfma_f32_16x16x32_bf16(ph0, bh[T], acc[0][T], 0, 0, 0);
            acc[0][T] = __builtin_amdgcn_mfma_f32_16x16x32_bf16(pl0, bh[T], acc[0][T], 0, 0, 0);
            acc[0][T] = __builtin_amdgcn_mfma_f32_16x16x32_bf16(ph0, bl[T], acc[0][T], 0, 0, 0);
            acc[1][T] = __builtin_amdgcn_mfma_f32_16x16x32_bf16(ph1, bh[T], acc[1][T], 0, 0, 0);
            acc[1][T] = __builtin_amdgcn_mfma_f32_16x16x32_bf16(pl1, bh[T], acc[1][T], 0, 0, 0);
            acc[1][T] = __builtin_amdgcn_mfma_f32_16x16x32_bf16(ph1, bl[T], acc[1][T], 0, 0, 0);
        }
    };

    // double-buffered, barrier-free main loop over this wave's J-half
    bf16x8 bhA[4], blA[4], bhB[4], blB[4];
    loadB(J0, bhA, blA);
    #pragma unroll 1
    for (int Jt = 0; Jt < 16; Jt += 2) {
        loadB(J0 + Jt + 1, bhB, blB);               // prefetch next J
        compute(J0 + Jt, bhA, blA);
        if (Jt + 2 < 16) loadB(J0 + Jt + 2, bhA, blA);
        compute(J0 + Jt + 1, bhB, blB);
    }

    // reduce lsum over k-strips: lanes {m, m+16, m+32, m+48} -> row totals
    ls0 += __shfl_xor(ls0, 16, 64); ls0 += __shfl_xor(ls0, 32, 64);
    ls1 += __shfl_xor(ls1, 16, 64); ls1 += __shfl_xor(ls1, 32, 64);
    if (lane < 16) { lsW[wid][0][lane] = ls0; lsW[wid][1][lane] = ls1; }

    // exchange the rt this wave does NOT finish (rt = 1-jh); jh is
    // wave-uniform so the ternary is a register select, never a runtime index
    #pragma unroll
    for (int T = 0; T < 4; ++T)
        accX[wid][T][lane] = jh ? acc[0][T] : acc[1][T];
    __syncthreads();

    // finish rt = jh: combine both J-halves, normalize, ELU, store
    const int rq = lane >> 4;
    float rvv[4];
    #pragma unroll
    for (int r = 0; r < 4; ++r) {
        int row = rq * 4 + r;                       // C/D row within 16
        rvv[r] = 1.0f / (lsW[2 * p][jh][row] + lsW[2 * p + 1][jh][row]);
    }
    const int colbase = lane & 15;
    const int orow0   = i0 + p * 32 + jh * 16;
    #pragma unroll
    for (int T = 0; T < 4; ++T) {
        f32x4 mine = jh ? acc[1][T] : acc[0][T];
        f32x4 oth  = accX[wid ^ 1][T][lane];
        #pragma unroll
        for (int r = 0; r < 4; ++r) {
            int   rr = rq * 4 + r;
            float v  = (mine[r] + oth[r]) * rvv[r];
            v = v > 0.f ? v : expm1f(v);            // final ELU
            out[(size_t)(n * SQ + orow0 + rr) * OUTF + T * 16 + colbase] = v;
        }
    }
}

extern "C" void kernel_launch(void* const* d_in, const int* in_sizes, int n_in,
                              void* d_out, int out_size, void* d_ws, size_t ws_size,
                              hipStream_t stream) {
    const float* h = (const float*)d_in[0];
    // d_in[1] = adj : unused by the reference computation
    const float* W = (const float*)d_in[2];
    const float* a = (const float*)d_in[3];

    char* ws = (char*)d_ws;
    __bf16* whmH = (__bf16*)ws;                                   // 4 MB
    __bf16* whmL = (__bf16*)(ws + (size_t)4 * 1024 * 1024);       // 4 MB
    float*  fb   = (float*)(ws + (size_t)8 * 1024 * 1024);        // 128 KB
    float*  gb   = (float*)(ws + (size_t)8 * 1024 * 1024 + 131072);
    float*  outp = (float*)d_out;

    hipLaunchKernelGGL(kA, dim3(512), dim3(256), 0, stream, h, W, a, whmH, whmL, fb, gb);
    hipLaunchKernelGGL(kC, dim3(512), dim3(256), 0, stream, whmH, whmL, fb, gb, outp);
}